// Round 2
// baseline (324.387 us; speedup 1.0000x reference)
//
#include <hip/hip_runtime.h>
#include <hip/hip_fp16.h>

// Problem constants
#define BB    16
#define LL    48000
#define WW    64
#define LWT   512
#define NELEM (BB*LL)      // 768000
#define NGRP  (NELEM/4)    // 192000 groups of 4 elements
#define RATIO (512.0/16000.0)
#define EPT   48           // elements per thread in prelude (1000 active threads)
#define KD_BLOCKS 512
#define KD_WAVES  (KD_BLOCKS*16)   // 8192 waves, 1024 threads/block

// ---------------- Kernel P: fused scan + index/alpha pack ------------------
// One block per batch row. Phase 1: per-thread fp64 sum of its 48 increments.
// Block scan over thread sums. Phase 2: running fp64 prefix -> index, alpha,
// packed (9-bit idx | 23-bit alpha) per element.
__global__ __launch_bounds__(1024) void kP(const float* __restrict__ pitch,
                                           unsigned* __restrict__ packed) {
    const int r = blockIdx.x;
    const int t = threadIdx.x;
    const bool act = (t < 1000);          // 1000 * 48 = 48000
    const int e0 = t * EPT;
    const float* prow = pitch + (size_t)r * LL;

    double s = 0.0;
    if (act) {
        for (int k = 0; k < EPT; k++) s += RATIO * (double)prow[e0 + k];
    }
    // wave-inclusive scan of thread sums
    const int lane = t & 63, wv = t >> 6;
    double inc = s;
    for (int d = 1; d < 64; d <<= 1) {
        double u = __shfl_up(inc, d);
        if (lane >= d) inc += u;
    }
    __shared__ double wsum[16];
    if (lane == 63) wsum[wv] = inc;
    __syncthreads();
    double wb = 0.0;
    for (int i = 0; i < wv; i++) wb += wsum[i];
    if (!act) return;
    double run = wb + inc - s;            // exclusive prefix for this thread

    const float* p0 = pitch;              // batch row 0: increment[0] broadcast
    unsigned* prow_out = packed + (size_t)r * LL;
    for (int k = 0; k < EPT; k++) {
        int l = e0 + k;
        run += RATIO * (double)prow[l];
        double idx = run - RATIO * (double)p0[l];   // cumsum - increment[0]
        // np.remainder (floor-division semantics; idx can be slightly negative)
        double m = idx - floor(idx * (1.0 / 512.0)) * 512.0;
        if (m < 0.0)    m += 512.0;
        if (m >= 512.0) m -= 512.0;
        if (512.0 - m < 1e-5) m = 0.0;
        double lowd = floor(m);
        double alpha = m - lowd;
        unsigned il = (unsigned)lowd;
        unsigned au = (unsigned)(alpha * 8388608.0 + 0.5);
        if (au > 0x7fffffu) au = 0x7fffffu;
        prow_out[l] = (il << 23) | au;
    }
}

// ---------------- Kernel D: main synthesis ---------------------------------
// 1024-thread blocks (16 waves), 64 KB LDS fp16 table [idx][w] -> 2 blocks/CU,
// 32 waves/CU. Wave handles 4 elements/iter: 16 lanes/element, lane = 4 w's.
// Round-robin group assignment for balance + contiguous grid-wide attn sweep.
__global__ __launch_bounds__(1024, 8) void kD(const float4* __restrict__ attn4,
                                              const float* __restrict__ env,
                                              const unsigned* __restrict__ packed,
                                              const float* __restrict__ wt,
                                              float* __restrict__ out) {
    __shared__ __half tab[LWT * WW];               // 65536 B
    for (int i = threadIdx.x; i < LWT * WW; i += 1024) {
        int w = i >> 9, idx = i & 511;             // wt is [w][idx], coalesced read
        tab[(idx << 6) | w] = __float2half(wt[i]);
    }
    __syncthreads();

    const int lane = threadIdx.x & 63;
    const int sub = lane >> 4;                     // element within group of 4
    const int li  = lane & 15;                     // w-quad index
    const int wid = (blockIdx.x << 4) | (threadIdx.x >> 6);  // 0..8191

    int g = wid;
    if (g >= NGRP) return;
    float4  a = attn4[(size_t)g * 64 + lane];      // prefetch (1 KB/wave)
    unsigned p = packed[(g << 2) | sub];
    while (true) {
        float4 ac = a;
        unsigned pc = p;
        int gn = g + KD_WAVES;
        if (gn < NGRP) {                           // 1-deep pipeline
            a = attn4[(size_t)gn * 64 + lane];
            p = packed[(gn << 2) | sub];
        }
        unsigned il = pc >> 23;
        float alpha = (float)(pc & 0x7fffffu) * (1.0f / 8388608.0f);
        unsigned ih = (il + 1) & 511;
        uint2 lo = *(const uint2*)(tab + (il << 6) + (li << 2));
        uint2 hi = *(const uint2*)(tab + (ih << 6) + (li << 2));
        __half2 l01 = *(__half2*)&lo.x, l23 = *(__half2*)&lo.y;
        __half2 h01 = *(__half2*)&hi.x, h23 = *(__half2*)&hi.y;
        float2 fl01 = __half22float2(l01), fl23 = __half22float2(l23);
        float2 fh01 = __half22float2(h01), fh23 = __half22float2(h23);
        float w0 = fmaf(alpha, fh01.x - fl01.x, fl01.x);
        float w1 = fmaf(alpha, fh01.y - fl01.y, fl01.y);
        float w2 = fmaf(alpha, fh23.x - fl23.x, fl23.x);
        float w3 = fmaf(alpha, fh23.y - fl23.y, fl23.y);
        float sv = w0 * ac.x + w1 * ac.y + w2 * ac.z + w3 * ac.w;
        sv += __shfl_xor(sv, 1);
        sv += __shfl_xor(sv, 2);
        sv += __shfl_xor(sv, 4);
        sv += __shfl_xor(sv, 8);
        if (li == 0) {
            int e = (g << 2) | sub;
            out[e] = sv * env[e];
        }
        if (gn >= NGRP) break;
        g = gn;
    }
}

extern "C" void kernel_launch(void* const* d_in, const int* in_sizes, int n_in,
                              void* d_out, int out_size, void* d_ws, size_t ws_size,
                              hipStream_t stream) {
    const float* pitch = (const float*)d_in[0];
    const float* env   = (const float*)d_in[1];
    const float* attn  = (const float*)d_in[2];
    const float* wt    = (const float*)d_in[3];
    float* out = (float*)d_out;

    unsigned* packed = (unsigned*)d_ws;            // 3,072,000 B

    kP<<<BB, 1024, 0, stream>>>(pitch, packed);
    kD<<<KD_BLOCKS, 1024, 0, stream>>>((const float4*)attn, env, packed, wt, out);
}